// Round 1
// baseline (329.068 us; speedup 1.0000x reference)
//
#include <hip/hip_runtime.h>
#include <math.h>

// MoE: T=4096 tokens, D=1024, H=2048, O=1024, E=8 experts, top-2 routing.
// Sparse routed implementation: 68.7 GFLOP bf16 MFMA vs reference's dense 275 GFLOP fp32.

#define T_TOK 4096
#define DIM   1024
#define HID   2048
#define OUTD  1024
#define NE    8

typedef __bf16 bf16_t;
typedef __bf16 bf16x8 __attribute__((ext_vector_type(8)));
typedef float  f32x4  __attribute__((ext_vector_type(4)));

typedef __attribute__((address_space(3))) void       as3_void;
typedef __attribute__((address_space(1))) const void as1_void;
#define GLDS16(src, dst) \
  __builtin_amdgcn_global_load_lds((as1_void*)(src), (as3_void*)(dst), 16, 0, 0)

// ---------------- gating: logits (fp64 acc), top-2, softmax, expert lists ---
__global__ void k_gate(const float* __restrict__ x, const float* __restrict__ Wg,
                       const float* __restrict__ bg, int* cnt, int* elist,
                       float* egate) {
  int wid  = threadIdx.x >> 6;
  int lane = threadIdx.x & 63;
  int t = blockIdx.x * 4 + wid;
  double s[NE];
#pragma unroll
  for (int e = 0; e < NE; ++e) s[e] = 0.0;
  for (int d = lane; d < DIM; d += 64) {
    double xv = (double)x[(size_t)t * DIM + d];
#pragma unroll
    for (int e = 0; e < NE; ++e) s[e] += xv * (double)Wg[d * NE + e];
  }
#pragma unroll
  for (int off = 32; off > 0; off >>= 1) {
#pragma unroll
    for (int e = 0; e < NE; ++e) s[e] += __shfl_xor(s[e], off);
  }
  if (lane == 0) {
    double v0 = -1e300, v1 = -1e300;
    int i0 = 0, i1 = 0;
#pragma unroll
    for (int e = 0; e < NE; ++e) {
      double v = s[e] + (double)bg[e];
      if (v > v0)      { v1 = v0; i1 = i0; v0 = v; i0 = e; }
      else if (v > v1) { v1 = v;  i1 = e; }
    }
    // softmax over [v0, v1]
    float ex = expf((float)(v1 - v0));
    float inv = 1.0f / (1.0f + ex);
    float g0 = inv, g1 = ex * inv;
    int p0 = atomicAdd(&cnt[i0], 1);
    elist[i0 * T_TOK + p0] = t;  egate[i0 * T_TOK + p0] = g0;
    int p1 = atomicAdd(&cnt[i1], 1);
    elist[i1 * T_TOK + p1] = t;  egate[i1 * T_TOK + p1] = g1;
  }
}

__global__ void k_offs(const int* cnt, int* offs) {
  if (threadIdx.x == 0) {
    int a = 0;
    for (int e = 0; e < NE; ++e) { offs[e] = a; a += cnt[e]; }
    offs[NE] = a;
  }
}

// ---------------- x fp32 -> bf16 --------------------------------------------
__global__ void k_cvt_x(const float* __restrict__ x, bf16_t* __restrict__ xb) {
  int n4 = T_TOK * DIM / 4;
  for (int i = blockIdx.x * blockDim.x + threadIdx.x; i < n4;
       i += gridDim.x * blockDim.x) {
    float4 v = ((const float4*)x)[i];
    union { bf16_t b[4]; ushort4 u; } cv;
    cv.b[0] = (bf16_t)v.x; cv.b[1] = (bf16_t)v.y;
    cv.b[2] = (bf16_t)v.z; cv.b[3] = (bf16_t)v.w;
    ((ushort4*)xb)[i] = cv.u;
  }
}

// ------------- per-expert transpose + convert: W[R][C] -> Wt[C][R] bf16 -----
__global__ void k_tr(const float* __restrict__ W, bf16_t* __restrict__ Wt,
                     int R, int C) {
  __shared__ float tile[32][33];
  size_t ebase = (size_t)blockIdx.z * R * C;
  int c0 = blockIdx.x * 32, r0 = blockIdx.y * 32;
  int tx = threadIdx.x, ty = threadIdx.y;
#pragma unroll
  for (int i = 0; i < 4; ++i)
    tile[ty + i * 8][tx] = W[ebase + (size_t)(r0 + ty + i * 8) * C + c0 + tx];
  __syncthreads();
#pragma unroll
  for (int i = 0; i < 4; ++i)
    Wt[ebase + (size_t)(c0 + ty + i * 8) * R + r0 + tx] =
        (bf16_t)tile[tx][ty + i * 8];
}

// ---------------- GEMM1: h = relu(gather(x) @ W1 + b1) ----------------------
// A: gathered xb rows (count_e x 1024), B: W1t[e] = [h][d], out: h bf16.
__launch_bounds__(256, 2)
__global__ void k_gemm1(const bf16_t* __restrict__ xb, const bf16_t* __restrict__ W1t,
                        const float* __restrict__ b1, const int* __restrict__ cnt,
                        const int* __restrict__ offs, const int* __restrict__ elist,
                        bf16_t* __restrict__ h) {
  int e = blockIdx.z;
  int count = cnt[e];
  int rt = blockIdx.y;
  if (rt * 128 >= count) return;
  int nt = blockIdx.x;

  __shared__ bf16_t As[128][32];
  __shared__ bf16_t Bs[128][32];

  int tid = threadIdx.x;
  int lane = tid & 63, wid = tid >> 6;
  int wr = (wid >> 1) * 64, wc = (wid & 1) * 64;

  const bf16_t* srcA[2];
  const bf16_t* srcB[2];
#pragma unroll
  for (int i = 0; i < 2; ++i) {
    int c = tid + 256 * i;
    int row = c >> 2, kc = (c & 3) * 8;
    int gr = rt * 128 + row;
    if (gr > count - 1) gr = count - 1;
    int tok = elist[e * T_TOK + gr];
    srcA[i] = xb + (size_t)tok * DIM + kc;
    srcB[i] = W1t + ((size_t)e * HID + nt * 128 + row) * DIM + kc;
  }

  f32x4 acc[4][4] = {};
  int fr = lane & 15, fg = (lane >> 4) * 8;

  for (int kt = 0; kt < DIM / 32; ++kt) {
#pragma unroll
    for (int i = 0; i < 2; ++i) {
      int c = tid + 256 * i;
      GLDS16(srcA[i] + kt * 32, ((char*)As) + c * 16);
      GLDS16(srcB[i] + kt * 32, ((char*)Bs) + c * 16);
    }
    __syncthreads();
    bf16x8 a[4], b[4];
#pragma unroll
    for (int mi = 0; mi < 4; ++mi) a[mi] = *(const bf16x8*)&As[wr + mi * 16 + fr][fg];
#pragma unroll
    for (int ni = 0; ni < 4; ++ni) b[ni] = *(const bf16x8*)&Bs[wc + ni * 16 + fr][fg];
#pragma unroll
    for (int mi = 0; mi < 4; ++mi)
#pragma unroll
      for (int ni = 0; ni < 4; ++ni)
        acc[mi][ni] = __builtin_amdgcn_mfma_f32_16x16x32_bf16(a[mi], b[ni],
                                                              acc[mi][ni], 0, 0, 0);
    __syncthreads();
  }

  int hbase = offs[e];
#pragma unroll
  for (int mi = 0; mi < 4; ++mi) {
#pragma unroll
    for (int rr = 0; rr < 4; ++rr) {
      int rowp = rt * 128 + wr + mi * 16 + (lane >> 4) * 4 + rr;
      if (rowp < count) {
        size_t hrow = (size_t)(hbase + rowp) * HID;
#pragma unroll
        for (int ni = 0; ni < 4; ++ni) {
          int col = nt * 128 + wc + ni * 16 + (lane & 15);
          float v = acc[mi][ni][rr] + b1[e * HID + col];
          h[hrow + col] = (bf16_t)(v > 0.f ? v : 0.f);
        }
      }
    }
  }
}

// ---------------- GEMM2: out += gate * (h @ W2 + b2) ------------------------
__launch_bounds__(256, 2)
__global__ void k_gemm2(const bf16_t* __restrict__ h, const bf16_t* __restrict__ W2t,
                        const float* __restrict__ b2, const int* __restrict__ cnt,
                        const int* __restrict__ offs, const int* __restrict__ elist,
                        const float* __restrict__ egate, float* __restrict__ out) {
  int e = blockIdx.z;
  int count = cnt[e];
  int rt = blockIdx.y;
  if (rt * 128 >= count) return;
  int nt = blockIdx.x;

  __shared__ bf16_t As[128][32];
  __shared__ bf16_t Bs[128][32];

  int tid = threadIdx.x;
  int lane = tid & 63, wid = tid >> 6;
  int wr = (wid >> 1) * 64, wc = (wid & 1) * 64;
  int hbase = offs[e];

  const bf16_t* srcA[2];
  const bf16_t* srcB[2];
#pragma unroll
  for (int i = 0; i < 2; ++i) {
    int c = tid + 256 * i;
    int row = c >> 2, kc = (c & 3) * 8;
    int gr = rt * 128 + row;
    if (gr > count - 1) gr = count - 1;
    srcA[i] = h + (size_t)(hbase + gr) * HID + kc;
    srcB[i] = W2t + ((size_t)e * OUTD + nt * 128 + row) * HID + kc;
  }

  f32x4 acc[4][4] = {};
  int fr = lane & 15, fg = (lane >> 4) * 8;

  for (int kt = 0; kt < HID / 32; ++kt) {
#pragma unroll
    for (int i = 0; i < 2; ++i) {
      int c = tid + 256 * i;
      GLDS16(srcA[i] + kt * 32, ((char*)As) + c * 16);
      GLDS16(srcB[i] + kt * 32, ((char*)Bs) + c * 16);
    }
    __syncthreads();
    bf16x8 a[4], b[4];
#pragma unroll
    for (int mi = 0; mi < 4; ++mi) a[mi] = *(const bf16x8*)&As[wr + mi * 16 + fr][fg];
#pragma unroll
    for (int ni = 0; ni < 4; ++ni) b[ni] = *(const bf16x8*)&Bs[wc + ni * 16 + fr][fg];
#pragma unroll
    for (int mi = 0; mi < 4; ++mi)
#pragma unroll
      for (int ni = 0; ni < 4; ++ni)
        acc[mi][ni] = __builtin_amdgcn_mfma_f32_16x16x32_bf16(a[mi], b[ni],
                                                              acc[mi][ni], 0, 0, 0);
    __syncthreads();
  }

#pragma unroll
  for (int mi = 0; mi < 4; ++mi) {
#pragma unroll
    for (int rr = 0; rr < 4; ++rr) {
      int rowp = rt * 128 + wr + mi * 16 + (lane >> 4) * 4 + rr;
      if (rowp < count) {
        int tok    = elist[e * T_TOK + rowp];
        float gate = egate[e * T_TOK + rowp];
#pragma unroll
        for (int ni = 0; ni < 4; ++ni) {
          int col = nt * 128 + wc + ni * 16 + (lane & 15);
          float v = (acc[mi][ni][rr] + b2[e * OUTD + col]) * gate;
          atomicAdd(&out[(size_t)tok * OUTD + col], v);
        }
      }
    }
  }
}

// ---------------------------------------------------------------------------
extern "C" void kernel_launch(void* const* d_in, const int* in_sizes, int n_in,
                              void* d_out, int out_size, void* d_ws, size_t ws_size,
                              hipStream_t stream) {
  const float* x  = (const float*)d_in[0];
  const float* Wg = (const float*)d_in[1];
  const float* bg = (const float*)d_in[2];
  const float* W1 = (const float*)d_in[3];
  const float* b1 = (const float*)d_in[4];
  const float* W2 = (const float*)d_in[5];
  const float* b2 = (const float*)d_in[6];
  float* out = (float*)d_out;

  char* ws = (char*)d_ws;
  // workspace layout (needs ~110 MB)
  int*   cnt   = (int*)(ws);               // 32 B
  int*   offs  = (int*)(ws + 256);         // 36 B
  int*   elist = (int*)(ws + 1024);        // 8*4096*4 = 128 KB
  float* egate = (float*)(ws + 1024 + NE * T_TOK * 4);
  size_t cur = 1024 + (size_t)2 * NE * T_TOK * 4;  // 263168, 256-aligned
  bf16_t* W1t  = (bf16_t*)(ws + cur); cur += (size_t)NE * DIM * HID * 2;   // 32 MB
  bf16_t* W2t  = (bf16_t*)(ws + cur); cur += (size_t)NE * HID * OUTD * 2;  // 32 MB
  bf16_t* xb   = (bf16_t*)(ws + cur); cur += (size_t)T_TOK * DIM * 2;      // 8 MB
  bf16_t* hbuf = (bf16_t*)(ws + cur); cur += (size_t)T_TOK * 2 * HID * 2;  // 32 MB

  hipMemsetAsync(cnt, 0, 1024, stream);
  hipMemsetAsync(out, 0, (size_t)out_size * sizeof(float), stream);

  k_cvt_x<<<2048, 256, 0, stream>>>(x, xb);
  k_tr<<<dim3(HID / 32, DIM / 32, NE), dim3(32, 8), 0, stream>>>(W1, W1t, DIM, HID);
  k_tr<<<dim3(OUTD / 32, HID / 32, NE), dim3(32, 8), 0, stream>>>(W2, W2t, HID, OUTD);
  k_gate<<<T_TOK / 4, 256, 0, stream>>>(x, Wg, bg, cnt, elist, egate);
  k_offs<<<1, 1, 0, stream>>>(cnt, offs);

  k_gemm1<<<dim3(HID / 128, T_TOK / 128, NE), 256, 0, stream>>>(
      xb, W1t, b1, cnt, offs, elist, hbuf);
  k_gemm2<<<dim3(OUTD / 128, T_TOK / 128, NE), 256, 0, stream>>>(
      hbuf, W2t, b2, cnt, offs, elist, egate, out);
}

// Round 2
// 305.577 us; speedup vs baseline: 1.0769x; 1.0769x over previous
//
#include <hip/hip_runtime.h>
#include <math.h>

// MoE: T=4096, D=1024, H=2048, O=1024, E=8, top-2.
// Routed sparse: 68.7 GFLOP bf16 MFMA. GEMMs use 256x256/BK=64 8-wave 8-phase
// schedule (T2 chunk-XOR swizzle + T3/T4 counted vmcnt + T5 setprio).

#define T_TOK 4096
#define DIM   1024
#define HID   2048
#define OUTD  1024
#define NE    8

typedef __bf16 bf16_t;
typedef __bf16 bf16x8 __attribute__((ext_vector_type(8)));
typedef float  f32x4  __attribute__((ext_vector_type(4)));

typedef __attribute__((address_space(3))) void       as3_void;
typedef __attribute__((address_space(1))) const void as1_void;
#define GLDS16(src, dst) \
  __builtin_amdgcn_global_load_lds((as1_void*)(src), (as3_void*)(dst), 16, 0, 0)

#define FENCE() asm volatile("" ::: "memory")
#define BARRIER() do { FENCE(); __builtin_amdgcn_s_barrier(); FENCE(); } while (0)

// ---------------- gating: logits (fp64 acc), top-2, softmax, expert lists ---
__global__ void k_gate(const float* __restrict__ x, const float* __restrict__ Wg,
                       const float* __restrict__ bg, int* cnt, int* elist,
                       float* egate, int* tokrec) {
  int wid  = threadIdx.x >> 6;
  int lane = threadIdx.x & 63;
  int t = blockIdx.x * 4 + wid;
  double s[NE];
#pragma unroll
  for (int e = 0; e < NE; ++e) s[e] = 0.0;
  for (int d = lane; d < DIM; d += 64) {
    double xv = (double)x[(size_t)t * DIM + d];
#pragma unroll
    for (int e = 0; e < NE; ++e) s[e] += xv * (double)Wg[d * NE + e];
  }
#pragma unroll
  for (int off = 32; off > 0; off >>= 1) {
#pragma unroll
    for (int e = 0; e < NE; ++e) s[e] += __shfl_xor(s[e], off);
  }
  if (lane == 0) {
    double v0 = -1e300, v1 = -1e300;
    int i0 = 0, i1 = 0;
#pragma unroll
    for (int e = 0; e < NE; ++e) {
      double v = s[e] + (double)bg[e];
      if (v > v0)      { v1 = v0; i1 = i0; v0 = v; i0 = e; }
      else if (v > v1) { v1 = v;  i1 = e; }
    }
    float ex = expf((float)(v1 - v0));
    float inv = 1.0f / (1.0f + ex);
    float g0 = inv, g1 = ex * inv;
    int p0 = atomicAdd(&cnt[i0], 1);
    elist[i0 * T_TOK + p0] = t;  egate[i0 * T_TOK + p0] = g0;
    int p1 = atomicAdd(&cnt[i1], 1);
    elist[i1 * T_TOK + p1] = t;  egate[i1 * T_TOK + p1] = g1;
    tokrec[2 * t]     = (i0 << 16) | p0;
    tokrec[2 * t + 1] = (i1 << 16) | p1;
  }
}

__global__ void k_offs(const int* cnt, int* offs) {
  if (threadIdx.x == 0) {
    int a = 0;
    for (int e = 0; e < NE; ++e) { offs[e] = a; a += cnt[e]; }
    offs[NE] = a;
  }
}

// ---------------- x fp32 -> bf16 --------------------------------------------
__global__ void k_cvt_x(const float* __restrict__ x, bf16_t* __restrict__ xb) {
  int n4 = T_TOK * DIM / 4;
  for (int i = blockIdx.x * blockDim.x + threadIdx.x; i < n4;
       i += gridDim.x * blockDim.x) {
    float4 v = ((const float4*)x)[i];
    union { bf16_t b[4]; ushort4 u; } cv;
    cv.b[0] = (bf16_t)v.x; cv.b[1] = (bf16_t)v.y;
    cv.b[2] = (bf16_t)v.z; cv.b[3] = (bf16_t)v.w;
    ((ushort4*)xb)[i] = cv.u;
  }
}

// ------------- per-expert transpose + convert: W[R][C] -> Wt[C][R] bf16 -----
__global__ void k_tr(const float* __restrict__ W, bf16_t* __restrict__ Wt,
                     int R, int C) {
  __shared__ float tile[32][33];
  size_t ebase = (size_t)blockIdx.z * R * C;
  int c0 = blockIdx.x * 32, r0 = blockIdx.y * 32;
  int id = threadIdx.x;
  int rc = id >> 5, cc = id & 31;
#pragma unroll
  for (int i = 0; i < 4; ++i)
    tile[rc + i * 8][cc] = W[ebase + (size_t)(r0 + rc + i * 8) * C + c0 + cc];
  __syncthreads();
  int oc = id >> 4, orp = id & 15;
  ushort2* wt2 = (ushort2*)(Wt + ebase);
#pragma unroll
  for (int i = 0; i < 2; ++i) {
    int c = oc + i * 16;
    union { bf16_t b[2]; ushort2 u; } cv;
    cv.b[0] = (bf16_t)tile[orp * 2][c];
    cv.b[1] = (bf16_t)tile[orp * 2 + 1][c];
    wt2[((size_t)(c0 + c) * R + r0 + orp * 2) >> 1] = cv.u;
  }
}

// ---------------- 8-phase 256x256 GEMM machinery ----------------------------
// LDS: A half-slots at smem + ((buf*2+half)<<14), B at +65536. Slot = 128x64 bf16.
// Swizzle: 16B chunk index ^= (row&7), applied on global SOURCE at staging and
// on ds_read address (both-sides involution).

#define STAGE_A(TT, HH) do { \
    char* _d = smem + ((((TT) & 1) * 2 + (HH)) << 14); \
    GLDS16(Abase + offA[HH][0] + (TT) * 128, _d + dstq0 * 16); \
    GLDS16(Abase + offA[HH][1] + (TT) * 128, _d + dstq1 * 16); } while (0)

#define STAGE_B(TT, HH) do { \
    char* _d = smem + 65536 + ((((TT) & 1) * 2 + (HH)) << 14); \
    GLDS16(Bbase + offB[HH][0] + (TT) * 128, _d + dstq0 * 16); \
    GLDS16(Bbase + offB[HH][1] + (TT) * 128, _d + dstq1 * 16); } while (0)

#define PHASE(Q, TT, NTc) do { \
    const char* _a  = smem + ((((TT) & 1) * 2 + ((Q) >> 1)) << 14); \
    const char* _bb = smem + 65536 + ((((TT) & 1) * 2 + ((Q) & 1)) << 14); \
    bf16x8 af[4][2], bfr[2][2]; \
    _Pragma("unroll") for (int i = 0; i < 4; ++i) \
      _Pragma("unroll") for (int kk = 0; kk < 2; ++kk) \
        af[i][kk] = *(const bf16x8*)(_a + rdA[i][kk]); \
    _Pragma("unroll") for (int j = 0; j < 2; ++j) \
      _Pragma("unroll") for (int kk = 0; kk < 2; ++kk) \
        bfr[j][kk] = *(const bf16x8*)(_bb + rdB[j][kk]); \
    if ((Q) == 0)      { if ((TT) + 1 < (NTc)) STAGE_A((TT) + 1, 1); } \
    else if ((Q) == 1) { if ((TT) + 1 < (NTc)) STAGE_B((TT) + 1, 1); } \
    else if ((Q) == 2) { if ((TT) + 2 < (NTc)) STAGE_A((TT) + 2, 0); } \
    else { \
      if ((TT) + 2 < (NTc)) { STAGE_B((TT) + 2, 0); \
        asm volatile("s_waitcnt vmcnt(4)" ::: "memory"); } \
      else { asm volatile("s_waitcnt vmcnt(0)" ::: "memory"); } \
    } \
    BARRIER(); \
    asm volatile("s_waitcnt lgkmcnt(0)" ::: "memory"); \
    __builtin_amdgcn_sched_barrier(0); \
    __builtin_amdgcn_s_setprio(1); \
    _Pragma("unroll") for (int i = 0; i < 4; ++i) \
      _Pragma("unroll") for (int j = 0; j < 2; ++j) \
        _Pragma("unroll") for (int kk = 0; kk < 2; ++kk) \
          acc[((Q) >> 1) * 4 + i][((Q) & 1) * 2 + j] = \
            __builtin_amdgcn_mfma_f32_16x16x32_bf16(af[i][kk], bfr[j][kk], \
                acc[((Q) >> 1) * 4 + i][((Q) & 1) * 2 + j], 0, 0, 0); \
    __builtin_amdgcn_s_setprio(0); \
    BARRIER(); \
  } while (0)

// ---------------- GEMM1: h = relu(gather(x) @ W1 + b1) ----------------------
__launch_bounds__(512, 2)
__global__ void k_gemm1(const bf16_t* __restrict__ xb, const bf16_t* __restrict__ W1t,
                        const float* __restrict__ b1, const int* __restrict__ cnt,
                        const int* __restrict__ offs, const int* __restrict__ elist,
                        bf16_t* __restrict__ hbuf) {
  const int e = blockIdx.z;
  const int count = cnt[e];
  const int rt = blockIdx.y;
  if (rt * 256 >= count) return;
  const int nt = blockIdx.x;

  __shared__ __align__(16) char smem[131072];

  const int tid = threadIdx.x, lane = tid & 63, wid = tid >> 6;
  const int wm = wid >> 2, wn = wid & 3;
  const int fr = lane & 15, lh = lane >> 4;

  // staging source byte-offsets: thread covers chunks q=j*512+tid
  unsigned offA[2][2], offB[2][2];
  const int dstq0 = tid, dstq1 = 512 + tid;
#pragma unroll
  for (int j = 0; j < 2; ++j) {
    int q = j * 512 + tid;
    int r = q >> 3, sfg = (q & 7) ^ (r & 7);
#pragma unroll
    for (int h = 0; h < 2; ++h) {
      int gr = rt * 256 + h * 128 + r;
      if (gr > count - 1) gr = count - 1;
      int tok = elist[e * T_TOK + gr];
      offA[h][j] = (unsigned)((tok * DIM + sfg * 8) * 2);
      int brow = nt * 256 + h * 128 + r;
      offB[h][j] = (unsigned)(((e * HID + brow) * DIM + sfg * 8) * 2);
    }
  }
  // ds_read byte-offsets (slot-local), swizzled
  unsigned rdA[4][2], rdB[2][2];
#pragma unroll
  for (int i = 0; i < 4; ++i) {
    int r = wm * 64 + i * 16 + fr;
#pragma unroll
    for (int kk = 0; kk < 2; ++kk)
      rdA[i][kk] = (unsigned)(r * 128 + (((kk * 4 + lh) ^ (r & 7)) * 16));
  }
#pragma unroll
  for (int j = 0; j < 2; ++j) {
    int r = wn * 32 + j * 16 + fr;
#pragma unroll
    for (int kk = 0; kk < 2; ++kk)
      rdB[j][kk] = (unsigned)(r * 128 + (((kk * 4 + lh) ^ (r & 7)) * 16));
  }

  const char* Abase = (const char*)xb;
  const char* Bbase = (const char*)W1t;

  f32x4 acc[8][4];
#pragma unroll
  for (int i = 0; i < 8; ++i)
#pragma unroll
    for (int j = 0; j < 4; ++j) acc[i][j] = (f32x4){0.f, 0.f, 0.f, 0.f};

  const int NT = DIM / 64;  // 16
  // prologue: A0(0) B0(0) A1(0) B1(0) A0(1) B0(1); keep last 4 loads in flight
  STAGE_A(0, 0); STAGE_B(0, 0); STAGE_A(0, 1); STAGE_B(0, 1);
  STAGE_A(1, 0); STAGE_B(1, 0);
  asm volatile("s_waitcnt vmcnt(4)" ::: "memory");
  BARRIER();

  for (int t = 0; t < NT; ++t) {
    PHASE(0, t, NT);
    PHASE(1, t, NT);
    PHASE(2, t, NT);
    PHASE(3, t, NT);
  }

  const int hbase = offs[e];
#pragma unroll
  for (int mi = 0; mi < 8; ++mi) {
#pragma unroll
    for (int rr = 0; rr < 4; ++rr) {
      int rowp = rt * 256 + (mi >> 2) * 128 + wm * 64 + (mi & 3) * 16 + lh * 4 + rr;
      if (rowp < count) {
        size_t hrow = (size_t)(hbase + rowp) * HID;
#pragma unroll
        for (int nj = 0; nj < 4; ++nj) {
          int col = nt * 256 + (nj >> 1) * 128 + wn * 32 + (nj & 1) * 16 + fr;
          float v = acc[mi][nj][rr] + b1[e * HID + col];
          hbuf[hrow + col] = (bf16_t)(v > 0.f ? v : 0.f);
        }
      }
    }
  }
}

// ---------------- GEMM2: y[slot] = gate * (h @ W2 + b2) ---------------------
__launch_bounds__(512, 2)
__global__ void k_gemm2(const bf16_t* __restrict__ hbuf, const bf16_t* __restrict__ W2t,
                        const float* __restrict__ b2, const int* __restrict__ cnt,
                        const int* __restrict__ offs, const float* __restrict__ egate,
                        float* __restrict__ y) {
  const int e = blockIdx.z;
  const int count = cnt[e];
  const int rt = blockIdx.y;
  if (rt * 256 >= count) return;
  const int nt = blockIdx.x;

  __shared__ __align__(16) char smem[131072];

  const int tid = threadIdx.x, lane = tid & 63, wid = tid >> 6;
  const int wm = wid >> 2, wn = wid & 3;
  const int fr = lane & 15, lh = lane >> 4;
  const int hbase = offs[e];

  unsigned offA[2][2], offB[2][2];
  const int dstq0 = tid, dstq1 = 512 + tid;
#pragma unroll
  for (int j = 0; j < 2; ++j) {
    int q = j * 512 + tid;
    int r = q >> 3, sfg = (q & 7) ^ (r & 7);
#pragma unroll
    for (int h = 0; h < 2; ++h) {
      int gr = rt * 256 + h * 128 + r;
      if (gr > count - 1) gr = count - 1;
      offA[h][j] = (unsigned)(((hbase + gr) * HID + sfg * 8) * 2);
      int brow = nt * 256 + h * 128 + r;
      offB[h][j] = (unsigned)(((e * OUTD + brow) * HID + sfg * 8) * 2);
    }
  }
  unsigned rdA[4][2], rdB[2][2];
#pragma unroll
  for (int i = 0; i < 4; ++i) {
    int r = wm * 64 + i * 16 + fr;
#pragma unroll
    for (int kk = 0; kk < 2; ++kk)
      rdA[i][kk] = (unsigned)(r * 128 + (((kk * 4 + lh) ^ (r & 7)) * 16));
  }
#pragma unroll
  for (int j = 0; j < 2; ++j) {
    int r = wn * 32 + j * 16 + fr;
#pragma unroll
    for (int kk = 0; kk < 2; ++kk)
      rdB[j][kk] = (unsigned)(r * 128 + (((kk * 4 + lh) ^ (r & 7)) * 16));
  }

  const char* Abase = (const char*)hbuf;
  const char* Bbase = (const char*)W2t;

  f32x4 acc[8][4];
#pragma unroll
  for (int i = 0; i < 8; ++i)
#pragma unroll
    for (int j = 0; j < 4; ++j) acc[i][j] = (f32x4){0.f, 0.f, 0.f, 0.f};

  const int NT = HID / 64;  // 32
  STAGE_A(0, 0); STAGE_B(0, 0); STAGE_A(0, 1); STAGE_B(0, 1);
  STAGE_A(1, 0); STAGE_B(1, 0);
  asm volatile("s_waitcnt vmcnt(4)" ::: "memory");
  BARRIER();

  for (int t = 0; t < NT; ++t) {
    PHASE(0, t, NT);
    PHASE(1, t, NT);
    PHASE(2, t, NT);
    PHASE(3, t, NT);
  }

#pragma unroll
  for (int mi = 0; mi < 8; ++mi) {
#pragma unroll
    for (int rr = 0; rr < 4; ++rr) {
      int rowp = rt * 256 + (mi >> 2) * 128 + wm * 64 + (mi & 3) * 16 + lh * 4 + rr;
      if (rowp < count) {
        float gate = egate[e * T_TOK + rowp];
        size_t yrow = (size_t)(hbase + rowp) * OUTD;
#pragma unroll
        for (int nj = 0; nj < 4; ++nj) {
          int col = nt * 256 + (nj >> 1) * 128 + wn * 32 + (nj & 1) * 16 + fr;
          y[yrow + col] = gate * (acc[mi][nj][rr] + b2[e * OUTD + col]);
        }
      }
    }
  }
}

// ---------------- combine: out[t] = y[slot0] + y[slot1] ---------------------
__global__ void k_combine(const float* __restrict__ y, const int* __restrict__ offs,
                          const int* __restrict__ tokrec, float* __restrict__ out) {
  int t = blockIdx.x;
  int r0 = tokrec[2 * t], r1 = tokrec[2 * t + 1];
  int s0 = offs[r0 >> 16] + (r0 & 0xffff);
  int s1 = offs[r1 >> 16] + (r1 & 0xffff);
  const float4* ya = (const float4*)(y + (size_t)s0 * OUTD);
  const float4* yb = (const float4*)(y + (size_t)s1 * OUTD);
  float4* o = (float4*)(out + (size_t)t * OUTD);
  int i = threadIdx.x;  // 256 threads x float4 = 1024 floats
  float4 a = ya[i], b = yb[i];
  o[i] = make_float4(a.x + b.x, a.y + b.y, a.z + b.z, a.w + b.w);
}

// ---------------------------------------------------------------------------
extern "C" void kernel_launch(void* const* d_in, const int* in_sizes, int n_in,
                              void* d_out, int out_size, void* d_ws, size_t ws_size,
                              hipStream_t stream) {
  const float* x  = (const float*)d_in[0];
  const float* Wg = (const float*)d_in[1];
  const float* bg = (const float*)d_in[2];
  const float* W1 = (const float*)d_in[3];
  const float* b1 = (const float*)d_in[4];
  const float* W2 = (const float*)d_in[5];
  const float* b2 = (const float*)d_in[6];
  float* out = (float*)d_out;

  char* ws = (char*)d_ws;
  int*    cnt    = (int*)(ws);
  int*    offs   = (int*)(ws + 1024);
  int*    tokrec = (int*)(ws + 4096);                       // 32 KB
  int*    elist  = (int*)(ws + 65536);                      // 128 KB
  float*  egate  = (float*)(ws + 262144);                   // 128 KB
  bf16_t* W1t    = (bf16_t*)(ws + (1u << 20));              // 32 MB
  float*  y      = (float*)(ws + (1u << 20));               // aliases W1t (dead by gemm2)
  bf16_t* W2t    = (bf16_t*)(ws + (1u << 20) + (32u << 20));// 32 MB
  bf16_t* xb     = (bf16_t*)(ws + (1u << 20) + (64u << 20));// 8 MB
  bf16_t* hbuf   = (bf16_t*)(ws + (1u << 20) + (72u << 20));// 32 MB

  hipMemsetAsync(cnt, 0, 1024, stream);

  k_cvt_x<<<2048, 256, 0, stream>>>(x, xb);
  k_tr<<<dim3(HID / 32, DIM / 32, NE), 256, 0, stream>>>(W1, W1t, DIM, HID);
  k_tr<<<dim3(OUTD / 32, HID / 32, NE), 256, 0, stream>>>(W2, W2t, HID, OUTD);
  k_gate<<<T_TOK / 4, 256, 0, stream>>>(x, Wg, bg, cnt, elist, egate, tokrec);
  k_offs<<<1, 1, 0, stream>>>(cnt, offs);

  k_gemm1<<<dim3(HID / 256, 16, NE), 512, 0, stream>>>(
      xb, W1t, b1, cnt, offs, elist, hbuf);
  k_gemm2<<<dim3(OUTD / 256, 16, NE), 512, 0, stream>>>(
      hbuf, W2t, b2, cnt, offs, egate, y);
  k_combine<<<T_TOK, 256, 0, stream>>>(y, offs, tokrec, out);
}